// Round 1
// baseline (78.002 us; speedup 1.0000x reference)
//
#include <hip/hip_runtime.h>
#include <math.h>

#define N 4096
#define G 8              // particles per block
#define BLK 256

#define EPSF 1e-8f
#define DTF 0.1f
#define PED_SPEEDF 1.4f
#define INV_MASS_DT (0.1f / 60.0f)

// mag = ALPHA * exp((2*R - d)/BETTA) = exp2(C0 - d*C1), ALPHA folded in:
// C1 = 1/(0.71*ln2), C0 = 0.6*C1 + log2(10)
#define C1F 2.0319658f
#define C0F 4.5331072f   // 0.6*2.0319658 + 3.3219281

__global__ __launch_bounds__(BLK) void step_kernel(
    const float4* __restrict__ state,   // (N,4): pos.xy, vel.xy
    const float2* __restrict__ goals,   // (N,2)
    float4* __restrict__ out)           // (N,4)
{
    const int tid = threadIdx.x;
    const int ibase = blockIdx.x * G;

    // uniform loads of this block's G particles (compiler -> s_load)
    float mex[G], mey[G];
#pragma unroll
    for (int g = 0; g < G; ++g) {
        float4 m = state[ibase + g];
        mex[g] = m.x; mey[g] = m.y;
    }

    float rfx[G], rfy[G];
#pragma unroll
    for (int g = 0; g < G; ++g) { rfx[g] = 0.0f; rfy[g] = 0.0f; }

    // stride over all j; self-term contributes exactly 0 (diff == 0)
    for (int j = tid; j < N; j += BLK) {
        float4 o = state[j];
        float ox = o.x, oy = o.y;
#pragma unroll
        for (int g = 0; g < G; ++g) {
            float dx = mex[g] - ox;
            float dy = mey[g] - oy;
            float d2 = fmaf(dx, dx, fmaf(dy, dy, EPSF));
            float inv = rsqrtf(d2);
            float d = d2 * inv;                       // sqrt(d2+eps)
            float mag = exp2f(fmaf(d, -C1F, C0F));    // ALPHA*exp((0.6-d)/0.71)
            float w = mag * inv;                      // mag / d
            rfx[g] = fmaf(w, dx, rfx[g]);
            rfy[g] = fmaf(w, dy, rfy[g]);
        }
    }

    // reduce across 256 threads: wave64 shuffle, then LDS across 4 waves
    __shared__ float sredx[4][G];
    __shared__ float sredy[4][G];
    const int wave = tid >> 6;
    const int lane = tid & 63;
#pragma unroll
    for (int g = 0; g < G; ++g) {
        float x = rfx[g], y = rfy[g];
#pragma unroll
        for (int off = 32; off > 0; off >>= 1) {
            x += __shfl_down(x, off);
            y += __shfl_down(y, off);
        }
        if (lane == 0) { sredx[wave][g] = x; sredy[wave][g] = y; }
    }
    __syncthreads();

    if (tid < G) {
        const int i = ibase + tid;
        float fx = sredx[0][tid] + sredx[1][tid] + sredx[2][tid] + sredx[3][tid];
        float fy = sredy[0][tid] + sredy[1][tid] + sredy[2][tid] + sredy[3][tid];

        float4 me = state[i];
        float px = me.x, py = me.y, vx = me.z, vy = me.w;
        float2 gl = goals[i];
        float tgx = gl.x - px, tgy = gl.y - py;
        float distg = sqrtf(fmaf(tgx, tgx, fmaf(tgy, tgy, EPSF)));
        float des = (i == 0) ? 1.0f : PED_SPEEDF;
        float s = des / distg;
        // af = K*(v_des - vel), K = 2
        float afx = 2.0f * (tgx * s - vx);
        float afy = 2.0f * (tgy * s - vy);

        float Fx = fx + afx, Fy = fy + afy;
        float vnx = fmaf(Fx, INV_MASS_DT, vx);
        float vny = fmaf(Fy, INV_MASS_DT, vy);
        float sp = sqrtf(fmaf(vnx, vnx, fmaf(vny, vny, EPSF)));
        float scale = fminf(1.0f, PED_SPEEDF / sp);
        vnx *= scale; vny *= scale;
        float pnx = fmaf(vnx, DTF, px);
        float pny = fmaf(vny, DTF, py);
        out[i] = make_float4(pnx, pny, vnx, vny);
    }
}

__global__ __launch_bounds__(BLK) void cost_kernel(
    const float* __restrict__ outbuf,        // (N,4) already updated
    const float* __restrict__ cost,          // (N,1)
    const float* __restrict__ rip,           // (2,)
    const float* __restrict__ goal,          // (2,)
    float* __restrict__ newcost)             // (N,1)
{
    const int i = blockIdx.x * BLK + threadIdx.x;
    float rx = outbuf[0], ry = outbuf[1];    // new robot pose
    float gx = goal[0], gy = goal[1];
    float ax = rip[0] - gx, ay = rip[1] - gy;
    float bx = rx - gx, by = ry - gy;
    float pg = sqrtf(fmaf(ax, ax, fmaf(ay, ay, EPSF)))
             - sqrtf(fmaf(bx, bx, fmaf(by, by, EPSF)));
    float dx = outbuf[i * 4 + 0] - rx;
    float dy = outbuf[i * 4 + 1] - ry;
    float dr = sqrtf(fmaf(dx, dx, fmaf(dy, dy, EPSF)));
    // temp = 5*pg + 2*exp(-dr/1.5); exp(x) = exp2(x*log2e)
    float e = exp2f(dr * (-1.4426950408889634f / 1.5f));
    newcost[i] = cost[i] + fmaf(5.0f, pg, 2.0f * e);
}

extern "C" void kernel_launch(void* const* d_in, const int* in_sizes, int n_in,
                              void* d_out, int out_size, void* d_ws, size_t ws_size,
                              hipStream_t stream) {
    const float* state = (const float*)d_in[0];
    const float* cost  = (const float*)d_in[1];
    const float* goals = (const float*)d_in[2];
    const float* rip   = (const float*)d_in[3];
    const float* goal  = (const float*)d_in[4];
    float* out = (float*)d_out;

    step_kernel<<<N / G, BLK, 0, stream>>>(
        (const float4*)state, (const float2*)goals, (float4*)out);
    cost_kernel<<<N / BLK, BLK, 0, stream>>>(
        out, cost, rip, goal, out + 4 * N);
}

// Round 2
// 70.713 us; speedup vs baseline: 1.1031x; 1.1031x over previous
//
#include <hip/hip_runtime.h>
#include <math.h>

#define N 4096
#define G 4              // particles per block
#define BLK 256
#define NJ (N / BLK)     // 16 j-iterations, compile-time constant -> full unroll

#define EPSF 1e-8f
#define DTF 0.1f
#define PED_SPEEDF 1.4f
#define INV_MASS_DT (0.1f / 60.0f)

// mag = ALPHA * exp((2*R - d)/BETTA) = exp2(C0 - d*C1), ALPHA folded in:
// C1 = 1/(0.71*ln2), C0 = 0.6*C1 + log2(10)
#define C1F 2.0319658f
#define C0F 4.5331072f

// Raw HW transcendentals: exactly one v_rsq_f32 / v_exp_f32, no ocml fixup code.
__device__ __forceinline__ float hw_rsq(float x)  { return __builtin_amdgcn_rsqf(x); }
__device__ __forceinline__ float hw_exp2(float x) { return __builtin_amdgcn_exp2f(x); }

__global__ __launch_bounds__(BLK, 4) void step_kernel(
    const float* __restrict__ state,    // (N,4): pos.xy, vel.xy
    const float2* __restrict__ goals,   // (N,2)
    float4* __restrict__ out)           // (N,4)
{
    const int tid = threadIdx.x;
    const int ibase = blockIdx.x * G;

    // uniform (block-constant) loads of this block's G particle positions
    float mex[G], mey[G];
#pragma unroll
    for (int g = 0; g < G; ++g) {
        mex[g] = state[(ibase + g) * 4 + 0];
        mey[g] = state[(ibase + g) * 4 + 1];
    }

    float rfx[G], rfy[G];
#pragma unroll
    for (int g = 0; g < G; ++g) { rfx[g] = 0.0f; rfy[g] = 0.0f; }

    const float2* pos2 = (const float2*)state;   // row j's position = pos2[2*j]

    // fully unrolled: 16 independent float2 loads batched ahead of the math;
    // self-term contributes exactly 0 (diff == 0), no branch needed
#pragma unroll
    for (int jj = 0; jj < NJ; ++jj) {
        float2 o = pos2[2 * (jj * BLK + tid)];
        float ox = o.x, oy = o.y;
#pragma unroll
        for (int g = 0; g < G; ++g) {
            float dx = mex[g] - ox;
            float dy = mey[g] - oy;
            float d2 = fmaf(dx, dx, fmaf(dy, dy, EPSF));
            float inv = hw_rsq(d2);
            float d = d2 * inv;                        // sqrt(d2+eps)
            float mag = hw_exp2(fmaf(d, -C1F, C0F));   // ALPHA*exp((0.6-d)/0.71)
            float w = mag * inv;                       // mag / d
            rfx[g] = fmaf(w, dx, rfx[g]);
            rfy[g] = fmaf(w, dy, rfy[g]);
        }
    }

    // reduce across 256 threads: wave64 shuffle, then LDS across 4 waves
    __shared__ float sredx[4][G];
    __shared__ float sredy[4][G];
    const int wave = tid >> 6;
    const int lane = tid & 63;
#pragma unroll
    for (int g = 0; g < G; ++g) {
        float x = rfx[g], y = rfy[g];
#pragma unroll
        for (int off = 32; off > 0; off >>= 1) {
            x += __shfl_down(x, off);
            y += __shfl_down(y, off);
        }
        if (lane == 0) { sredx[wave][g] = x; sredy[wave][g] = y; }
    }
    __syncthreads();

    if (tid < G) {
        const int i = ibase + tid;
        float fx = sredx[0][tid] + sredx[1][tid] + sredx[2][tid] + sredx[3][tid];
        float fy = sredy[0][tid] + sredy[1][tid] + sredy[2][tid] + sredy[3][tid];

        float px = state[i * 4 + 0], py = state[i * 4 + 1];
        float vx = state[i * 4 + 2], vy = state[i * 4 + 3];
        float2 gl = goals[i];
        float tgx = gl.x - px, tgy = gl.y - py;
        float distg = sqrtf(fmaf(tgx, tgx, fmaf(tgy, tgy, EPSF)));
        float des = (i == 0) ? 1.0f : PED_SPEEDF;
        float s = des / distg;
        // af = K*(v_des - vel), K = 2
        float afx = 2.0f * (tgx * s - vx);
        float afy = 2.0f * (tgy * s - vy);

        float Fx = fx + afx, Fy = fy + afy;
        float vnx = fmaf(Fx, INV_MASS_DT, vx);
        float vny = fmaf(Fy, INV_MASS_DT, vy);
        float sp = sqrtf(fmaf(vnx, vnx, fmaf(vny, vny, EPSF)));
        float scale = fminf(1.0f, PED_SPEEDF / sp);
        vnx *= scale; vny *= scale;
        float pnx = fmaf(vnx, DTF, px);
        float pny = fmaf(vny, DTF, py);
        out[i] = make_float4(pnx, pny, vnx, vny);
    }
}

__global__ __launch_bounds__(BLK) void cost_kernel(
    const float* __restrict__ outbuf,        // (N,4) already updated
    const float* __restrict__ cost,          // (N,1)
    const float* __restrict__ rip,           // (2,)
    const float* __restrict__ goal,          // (2,)
    float* __restrict__ newcost)             // (N,1)
{
    const int i = blockIdx.x * BLK + threadIdx.x;
    float rx = outbuf[0], ry = outbuf[1];    // new robot pose
    float gx = goal[0], gy = goal[1];
    float ax = rip[0] - gx, ay = rip[1] - gy;
    float bx = rx - gx, by = ry - gy;
    float pg = sqrtf(fmaf(ax, ax, fmaf(ay, ay, EPSF)))
             - sqrtf(fmaf(bx, bx, fmaf(by, by, EPSF)));
    float dx = outbuf[i * 4 + 0] - rx;
    float dy = outbuf[i * 4 + 1] - ry;
    float dr = sqrtf(fmaf(dx, dx, fmaf(dy, dy, EPSF)));
    // temp = 5*pg + 2*exp(-dr/1.5); exp(x) = exp2(x*log2e)
    float e = hw_exp2(dr * (-1.4426950408889634f / 1.5f));
    newcost[i] = cost[i] + fmaf(5.0f, pg, 2.0f * e);
}

extern "C" void kernel_launch(void* const* d_in, const int* in_sizes, int n_in,
                              void* d_out, int out_size, void* d_ws, size_t ws_size,
                              hipStream_t stream) {
    const float* state = (const float*)d_in[0];
    const float* cost  = (const float*)d_in[1];
    const float* goals = (const float*)d_in[2];
    const float* rip   = (const float*)d_in[3];
    const float* goal  = (const float*)d_in[4];
    float* out = (float*)d_out;

    step_kernel<<<N / G, BLK, 0, stream>>>(state, (const float2*)goals, (float4*)out);
    cost_kernel<<<N / BLK, BLK, 0, stream>>>(out, cost, rip, goal, out + 4 * N);
}

// Round 3
// 70.226 us; speedup vs baseline: 1.1107x; 1.0069x over previous
//
#include <hip/hip_runtime.h>
#include <math.h>

#define N 4096
#define G 8               // particles per block (+1 redundant robot slot)
#define SLOTS (G + 1)
#define BLK 256
#define NJ (N / BLK)      // 16 j-iterations, compile-time -> full unroll

#define EPSF 1e-8f
#define DTF 0.1f
#define PED_SPEEDF 1.4f
#define INV_MASS_DT (0.1f / 60.0f)

// mag = ALPHA * exp((2*R - d)/BETTA) = exp2(C0 - d*C1), ALPHA folded in:
// C1 = 1/(0.71*ln2), C0 = 0.6*C1 + log2(10)
#define C1F 2.0319658f
#define C0F 4.5331072f

// Raw HW transcendentals: one v_rsq_f32 / v_exp_f32 per pair, no ocml fixup.
__device__ __forceinline__ float hw_rsq(float x)  { return __builtin_amdgcn_rsqf(x); }
__device__ __forceinline__ float hw_exp2(float x) { return __builtin_amdgcn_exp2f(x); }

// Fused: pairwise forces + integration + cost in ONE kernel.
// Cross-block dep on robot's new pose is removed by every block redundantly
// computing particle 0's force (slot G) -> identical result in all blocks.
__global__ __launch_bounds__(BLK, 2) void step_kernel(
    const float* __restrict__ state,    // (N,4): pos.xy, vel.xy
    const float* __restrict__ cost,     // (N,1)
    const float2* __restrict__ goals,   // (N,2)
    const float* __restrict__ rip,      // (2,)
    const float* __restrict__ goal,     // (2,)
    float4* __restrict__ out,           // (N,4)
    float* __restrict__ newcost)        // (N,1)
{
    const int tid = threadIdx.x;
    const int ibase = blockIdx.x * G;

    // block-uniform positions for this block's G particles + robot (particle 0)
    float mex[SLOTS], mey[SLOTS];
#pragma unroll
    for (int g = 0; g < G; ++g) {
        mex[g] = state[(ibase + g) * 4 + 0];
        mey[g] = state[(ibase + g) * 4 + 1];
    }
    mex[G] = state[0];
    mey[G] = state[1];

    float rfx[SLOTS], rfy[SLOTS];
#pragma unroll
    for (int g = 0; g < SLOTS; ++g) { rfx[g] = 0.0f; rfy[g] = 0.0f; }

    const float2* pos2 = (const float2*)state;   // row j's position = pos2[2*j]

    // self-term contributes exactly 0 (diff == 0): no branch needed
#pragma unroll
    for (int jj = 0; jj < NJ; ++jj) {
        float2 o = pos2[2 * (jj * BLK + tid)];
        float ox = o.x, oy = o.y;
#pragma unroll
        for (int g = 0; g < SLOTS; ++g) {
            float dx = mex[g] - ox;
            float dy = mey[g] - oy;
            float d2 = fmaf(dx, dx, fmaf(dy, dy, EPSF));
            float inv = hw_rsq(d2);
            float d = d2 * inv;                        // sqrt(d2+eps)
            float mag = hw_exp2(fmaf(d, -C1F, C0F));   // ALPHA*exp((0.6-d)/0.71)
            float w = mag * inv;                       // mag / d
            rfx[g] = fmaf(w, dx, rfx[g]);
            rfy[g] = fmaf(w, dy, rfy[g]);
        }
    }

    // reduce across 256 threads: wave64 shuffle, then LDS across 4 waves
    __shared__ float sredx[4][SLOTS];
    __shared__ float sredy[4][SLOTS];
    const int wave = tid >> 6;
    const int lane = tid & 63;
#pragma unroll
    for (int g = 0; g < SLOTS; ++g) {
        float x = rfx[g], y = rfy[g];
#pragma unroll
        for (int off = 32; off > 0; off >>= 1) {
            x += __shfl_down(x, off);
            y += __shfl_down(y, off);
        }
        if (lane == 0) { sredx[wave][g] = x; sredy[wave][g] = y; }
    }
    __syncthreads();

    if (tid < G) {
        const int i = ibase + tid;

        // --- robot (particle 0) update, redundant per block, bitwise identical ---
        float rbfx = sredx[0][G] + sredx[1][G] + sredx[2][G] + sredx[3][G];
        float rbfy = sredy[0][G] + sredy[1][G] + sredy[2][G] + sredy[3][G];
        float r_px = state[0], r_py = state[1], r_vx = state[2], r_vy = state[3];
        float2 rgl = goals[0];
        float rtgx = rgl.x - r_px, rtgy = rgl.y - r_py;
        float rdg = sqrtf(fmaf(rtgx, rtgx, fmaf(rtgy, rtgy, EPSF)));
        float rs = 1.0f / rdg;                      // robot des_speed = 1.0
        float rFx = rbfx + 2.0f * (rtgx * rs - r_vx);
        float rFy = rbfy + 2.0f * (rtgy * rs - r_vy);
        float rvnx = fmaf(rFx, INV_MASS_DT, r_vx);
        float rvny = fmaf(rFy, INV_MASS_DT, r_vy);
        float rsp = sqrtf(fmaf(rvnx, rvnx, fmaf(rvny, rvny, EPSF)));
        float rsc = fminf(1.0f, PED_SPEEDF / rsp);
        rvnx *= rsc; rvny *= rsc;
        float rpx = fmaf(rvnx, DTF, r_px);          // new robot pose
        float rpy = fmaf(rvny, DTF, r_py);

        // --- this particle's update ---
        float fx = sredx[0][tid] + sredx[1][tid] + sredx[2][tid] + sredx[3][tid];
        float fy = sredy[0][tid] + sredy[1][tid] + sredy[2][tid] + sredy[3][tid];

        float px = state[i * 4 + 0], py = state[i * 4 + 1];
        float vx = state[i * 4 + 2], vy = state[i * 4 + 3];
        float2 gl = goals[i];
        float tgx = gl.x - px, tgy = gl.y - py;
        float distg = sqrtf(fmaf(tgx, tgx, fmaf(tgy, tgy, EPSF)));
        float des = (i == 0) ? 1.0f : PED_SPEEDF;
        float s = des / distg;
        float Fx = fx + 2.0f * (tgx * s - vx);
        float Fy = fy + 2.0f * (tgy * s - vy);
        float vnx = fmaf(Fx, INV_MASS_DT, vx);
        float vny = fmaf(Fy, INV_MASS_DT, vy);
        float sp = sqrtf(fmaf(vnx, vnx, fmaf(vny, vny, EPSF)));
        float scale = fminf(1.0f, PED_SPEEDF / sp);
        vnx *= scale; vny *= scale;
        float pnx = fmaf(vnx, DTF, px);
        float pny = fmaf(vny, DTF, py);
        out[i] = make_float4(pnx, pny, vnx, vny);

        // --- cost, fused ---
        float gx = goal[0], gy = goal[1];
        float ax = rip[0] - gx, ay = rip[1] - gy;
        float bx = rpx - gx, by = rpy - gy;
        float pg = sqrtf(fmaf(ax, ax, fmaf(ay, ay, EPSF)))
                 - sqrtf(fmaf(bx, bx, fmaf(by, by, EPSF)));
        float dx = pnx - rpx, dy = pny - rpy;
        float dr = sqrtf(fmaf(dx, dx, fmaf(dy, dy, EPSF)));
        float e = hw_exp2(dr * (-1.4426950408889634f / 1.5f)); // exp(-dr/1.5)
        newcost[i] = cost[i] + fmaf(5.0f, pg, 2.0f * e);
    }
}

extern "C" void kernel_launch(void* const* d_in, const int* in_sizes, int n_in,
                              void* d_out, int out_size, void* d_ws, size_t ws_size,
                              hipStream_t stream) {
    const float* state = (const float*)d_in[0];
    const float* cost  = (const float*)d_in[1];
    const float* goals = (const float*)d_in[2];
    const float* rip   = (const float*)d_in[3];
    const float* goal  = (const float*)d_in[4];
    float* out = (float*)d_out;

    step_kernel<<<N / G, BLK, 0, stream>>>(
        state, cost, (const float2*)goals, rip, goal,
        (float4*)out, out + 4 * N);
}